// Round 15
// baseline (1575.031 us; speedup 1.0000x reference)
//
#include <hip/hip_runtime.h>
#include <hip/hip_bf16.h>
#include <hip/hip_fp16.h>

#define E_ 16
#define T_ 128

typedef _Float16 h2_t __attribute__((ext_vector_type(2)));
typedef _Float16 half4_t __attribute__((ext_vector_type(4)));
typedef _Float16 half8_t __attribute__((ext_vector_type(8)));
typedef float f32x4 __attribute__((ext_vector_type(4)));

__device__ __forceinline__ float apply_act(float v, int act) {
  if (act == 1) return tanhf(v);
  if (act == 2) { // jax.nn.gelu approximate=True
    const float c = 0.7978845608028654f;
    return 0.5f * v * (1.0f + tanhf(c * (v + 0.044715f * v * v * v)));
  }
  return v;
}

// ---- MFMA GEMM (unchanged from round 12, verified passing) ----
template<int NT>
__global__ void __launch_bounds__(256) gemm_mfma(
    const float* __restrict__ A, const float* __restrict__ W,
    const float* __restrict__ bias, float* __restrict__ C, float* __restrict__ part,
    int N, int K, int lda, int ldc,
    long sAe, long sWe, long sBe, long sCe,
    int S, int act)
{
  int n0 = blockIdx.x * (32 * NT);
  int e  = blockIdx.y;
  int s  = blockIdx.z;
  const float* Ae = A + (long)e * sAe;
  const float* We = W + (long)e * sWe;
  int kper = K / S;
  int kb = s * kper, ke2 = kb + kper;

  __shared__ _Float16 As[128 * 40];   // 10,240 B

  int tid  = threadIdx.x;
  int lane = tid & 63;
  int w    = tid >> 6;
  int wm   = (w >> 1) * 64;
  int wn   = (w & 1) * (16 * NT);
  int l16  = lane & 15;
  int lk   = lane >> 4;

  f32x4 acc[4][NT];
  #pragma unroll
  for (int i = 0; i < 4; ++i)
    #pragma unroll
    for (int j = 0; j < NT; ++j)
      acc[i][j] = (f32x4){0.f, 0.f, 0.f, 0.f};

  for (int k0 = kb; k0 < ke2; k0 += 32) {
    __syncthreads();
    #pragma unroll
    for (int i = 0; i < 4; ++i) {
      int idx = tid + 256 * i;
      int row = idx >> 3, k4 = idx & 7;
      float4 a4 = *(const float4*)(Ae + (long)row * lda + k0 + k4 * 4);
      half4_t hv;
      hv.x = (_Float16)a4.x; hv.y = (_Float16)a4.y;
      hv.z = (_Float16)a4.z; hv.w = (_Float16)a4.w;
      *(half4_t*)(&As[row * 40 + k4 * 4]) = hv;
    }
    __syncthreads();
    #pragma unroll
    for (int nt = 0; nt < NT; ++nt) {
      int ncol = n0 + wn + nt * 16 + l16;
      const float* Wc = We + (long)(k0 + lk * 8) * N + ncol;
      half8_t b;
      #pragma unroll
      for (int j = 0; j < 8; ++j) b[j] = (_Float16)Wc[(long)j * N];
      #pragma unroll
      for (int mt = 0; mt < 4; ++mt) {
        half8_t a = *(const half8_t*)(&As[(wm + mt * 16 + l16) * 40 + lk * 8]);
        acc[mt][nt] = __builtin_amdgcn_mfma_f32_16x16x32_f16(a, b, acc[mt][nt], 0, 0, 0);
      }
    }
  }

  if (S == 1) {
    #pragma unroll
    for (int mt = 0; mt < 4; ++mt)
      #pragma unroll
      for (int nt = 0; nt < NT; ++nt) {
        int col = n0 + wn + nt * 16 + l16;
        float bv = bias[(long)e * sBe + col];
        #pragma unroll
        for (int r = 0; r < 4; ++r) {
          int row = wm + mt * 16 + lk * 4 + r;
          C[(long)e * sCe + (long)row * ldc + col] = apply_act(acc[mt][nt][r] + bv, act);
        }
      }
  } else {
    float* pp = part + ((long)(s * gridDim.y + e) * 128) * N;
    #pragma unroll
    for (int mt = 0; mt < 4; ++mt)
      #pragma unroll
      for (int nt = 0; nt < NT; ++nt) {
        int col = n0 + wn + nt * 16 + l16;
        #pragma unroll
        for (int r = 0; r < 4; ++r) {
          int row = wm + mt * 16 + lk * 4 + r;
          pp[(long)row * N + col] = acc[mt][nt][r];
        }
      }
  }
}

// reduce split-K partials + bias + act -> C (unchanged)
__global__ void __launch_bounds__(256) reduce_ep(
    const float* __restrict__ part, const float* __restrict__ bias, float* __restrict__ C,
    int S, int N, int ldc, long sBe, long sCe, int act, int total, int Eb)
{
  int idx = blockIdx.x * 256 + threadIdx.x;
  if (idx >= total) return;
  int n = idx % N;
  int r = (idx / N) & 127;
  int e = idx / (N * 128);
  long sstride = (long)Eb * 128 * N;
  float v = 0.f;
  for (int s = 0; s < S; ++s) v += part[s * sstride + ((long)e * 128 + r) * N + n];
  v = apply_act(v + bias[(long)e * sBe + n], act);
  C[(long)e * sCe + (long)r * ldc + n] = v;
}

// ---- sequential RNN layer: h[t] = tanh(P[t] + h[t-1] @ Wh) -- MFMA version ----
// ONE workgroup per encoder, block 1024 (16 waves). Wave w owns cols
// [32w, 32w+32) over the full K=512 -> 32 B-frags/thread (2 col-halves x
// 16 k-tiles of v_mfma_f32_16x16x32_f16).
// REGISTER WALL (R14 post-mortem): at 16 waves/CU the file gives 128 regs/
// thread TOTAL. Arch VGPRs are hard-capped at 64 (=65536/block_threads), so
// AGPR budget is <=64. R14 asked for 128 AGPRs -> unsatisfiable constraints
// -> garbage register state -> NaN. Legal partition:
//   16 frags in AGPRs  (kt 0..7, both col-halves)  = exactly 64 AGPRs
//    7 frags in VGPRs  (ct0 kt8..11, ct1 kt8..10)  = 28 arch regs
//    9 frags in LDS    (ct0 kt12..15, ct1 kt11..15) = 147,456 B
// Total 64 AGPR + ~58 arch <= 128 -> launchable, zero scratch.
// Per step: 16 broadcast ds_read_b128 of h (same addr within quarter-wave ->
// LDS broadcast), 9 LDS B-frag reads (16 B/lane contiguous = full-rate),
// 32 builtin MFMAs (AV operands read AGPRs directly -- the asm "+a" pin sets
// the vreg class), tanh+write on lanes<16, 2 barriers.
// Fragment mappings identical to gemm_mfma (end-to-end validated R10-R12).
__global__ void
__attribute__((amdgpu_flat_work_group_size(1024, 1024)))
rnn_seq(
    const float* __restrict__ P,     // [T][E][512], pre-activation incl. bias
    const float* __restrict__ Wh,    // + e*sWe : [512][512]
    float* __restrict__ H,           // (t*E+e)*1536 + col (layer offset by caller)
    long sWe)
{
  __shared__ half8_t lwB[9 * 16 * 64];   // 147,456 B
  __shared__ _Float16 hbuf[512];         //   1,024 B

  int tid  = threadIdx.x;
  int lane = tid & 63;
  int w    = tid >> 6;               // wave 0..15
  int l16  = lane & 15;
  int lk   = lane >> 4;              // 0..3
  int e    = blockIdx.x;
  int colbase = w * 32;

  const float* W = Wh + (long)e * sWe;   // element (k,c) at W[k*512 + c]

  // B-frag for (ct, kt): col = colbase + ct*16 + l16, k = kt*32 + lk*8 + j
  auto loadfrag = [&](int ct, int kt) -> half8_t {
    const float* Wc = W + (long)(kt * 32 + lk * 8) * 512 + colbase + ct * 16 + l16;
    half8_t b;
    #pragma unroll
    for (int j = 0; j < 8; ++j) b[j] = (_Float16)Wc[(long)j * 512];
    return b;
  };

  // AGPR frags: kt 0..7, both col-halves (exactly 64 AGPRs)
  half8_t ba0[8], ba1[8];
  #pragma unroll
  for (int kt = 0; kt < 8; ++kt) {
    ba0[kt] = loadfrag(0, kt); asm("" : "+a"(ba0[kt]));
    ba1[kt] = loadfrag(1, kt); asm("" : "+a"(ba1[kt]));
  }
  // VGPR frags: ct0 kt8..11, ct1 kt8..10
  half8_t bv0[4], bv1[3];
  #pragma unroll
  for (int i = 0; i < 4; ++i) bv0[i] = loadfrag(0, 8 + i);
  #pragma unroll
  for (int i = 0; i < 3; ++i) bv1[i] = loadfrag(1, 8 + i);
  // LDS frags: slot s<4 -> (ct0, kt=12+s); s>=4 -> (ct1, kt=s+7) i.e. kt 11..15
  for (int s = 0; s < 9; ++s) {
    int ct = (s < 4) ? 0 : 1;
    int kt = (s < 4) ? (12 + s) : (s + 7);
    lwB[(s * 16 + w) * 64 + lane] = loadfrag(ct, kt);
  }
  if (tid < 256) ((uint32_t*)hbuf)[tid] = 0;   // h(-1) = 0
  __syncthreads();

  for (int t = 0; t < T_; ++t) {
    float p0 = 0.f, p1 = 0.f;
    if (lane < 16) {
      const float* Pp = P + ((long)t * E_ + e) * 512 + colbase + lane;
      p0 = Pp[0]; p1 = Pp[16];
    }
    f32x4 acc0 = {0.f, 0.f, 0.f, 0.f}, acc1 = {0.f, 0.f, 0.f, 0.f};
    // AGPR-resident k-tiles 0..7
    #pragma unroll
    for (int kt = 0; kt < 8; ++kt) {
      half8_t a = *(const half8_t*)(&hbuf[kt * 32 + lk * 8]);  // broadcast
      acc0 = __builtin_amdgcn_mfma_f32_16x16x32_f16(a, ba0[kt], acc0, 0, 0, 0);
      acc1 = __builtin_amdgcn_mfma_f32_16x16x32_f16(a, ba1[kt], acc1, 0, 0, 0);
    }
    // VGPR-resident k-tiles 8..11 (ct1 only to 10)
    #pragma unroll
    for (int i = 0; i < 4; ++i) {
      int kt = 8 + i;
      half8_t a = *(const half8_t*)(&hbuf[kt * 32 + lk * 8]);
      acc0 = __builtin_amdgcn_mfma_f32_16x16x32_f16(a, bv0[i], acc0, 0, 0, 0);
      if (i < 3)
        acc1 = __builtin_amdgcn_mfma_f32_16x16x32_f16(a, bv1[i], acc1, 0, 0, 0);
    }
    // LDS-resident: ct1 kt11 (slot 4)
    {
      half8_t a = *(const half8_t*)(&hbuf[11 * 32 + lk * 8]);
      half8_t b = lwB[(4 * 16 + w) * 64 + lane];
      acc1 = __builtin_amdgcn_mfma_f32_16x16x32_f16(a, b, acc1, 0, 0, 0);
    }
    // LDS-resident: kt 12..15, both col-halves (slots i / 5+i)
    #pragma unroll
    for (int i = 0; i < 4; ++i) {
      int kt = 12 + i;
      half8_t a  = *(const half8_t*)(&hbuf[kt * 32 + lk * 8]);
      half8_t b0 = lwB[(i * 16 + w) * 64 + lane];
      half8_t b1 = lwB[((5 + i) * 16 + w) * 64 + lane];
      acc0 = __builtin_amdgcn_mfma_f32_16x16x32_f16(a, b0, acc0, 0, 0, 0);
      acc1 = __builtin_amdgcn_mfma_f32_16x16x32_f16(a, b1, acc1, 0, 0, 0);
    }
    __syncthreads();                 // all hbuf reads complete before rewrite
    if (lane < 16) {
      // D rows replicated (all A rows = h); reg 0 holds y[col]
      float v0 = tanhf(acc0[0] + p0);
      float v1 = tanhf(acc1[0] + p1);
      int col = colbase + lane;
      float* Hp = H + ((long)t * E_ + e) * 1536;
      Hp[col] = v0; Hp[col + 16] = v1;
      hbuf[col] = (_Float16)v0;
      hbuf[col + 16] = (_Float16)v1;
    }
    __syncthreads();                 // new h visible for next step
  }
}

extern "C" void kernel_launch(void* const* d_in, const int* in_sizes, int n_in,
                              void* d_out, int out_size, void* d_ws, size_t ws_size,
                              hipStream_t stream)
{
  const float* x      = (const float*)d_in[0];
  const float* W_in0  = (const float*)d_in[1];
  const float* Wh0    = (const float*)d_in[2];
  const float* b0     = (const float*)d_in[3];
  const float* W_inr  = (const float*)d_in[4];
  const float* Wh_r   = (const float*)d_in[5];
  const float* b_r    = (const float*)d_in[6];
  const float* W_ff1  = (const float*)d_in[7];
  const float* b_ff1  = (const float*)d_in[8];
  const float* W_ff2  = (const float*)d_in[9];
  const float* b_ff2  = (const float*)d_in[10];
  const float* W_d0   = (const float*)d_in[11];
  const float* b_d0   = (const float*)d_in[12];
  const float* W_dmid = (const float*)d_in[13];
  const float* b_dmid = (const float*)d_in[14];
  const float* W_dout = (const float*)d_in[15];
  const float* b_dout = (const float*)d_in[16];
  float* ws = (float*)d_ws;

  // workspace layout (floats)
  float* h    = ws;                    // [T][E][3][512]  3,145,728
  float* P    = ws + 3145728;          // [T][E][512]     1,048,576
  float* FF   = ws + 4194304;          // [T][E][2048]    4,194,304
  float* ENC  = ws + 8388608;          // [T][E*512]      1,048,576
  float* Z0   = ws + 9437184;          // [128][2048]       262,144
  float* Z1   = ws + 9699328;
  float* Z2   = ws + 9961472;
  float* PART = ws + 10223616;         // split-K partials 2,097,152

  (void)in_sizes; (void)n_in; (void)out_size; (void)ws_size;

  dim3 blk(256);

  // P = x @ W_in0 + b0
  gemm_mfma<2><<<dim3(8,16,1), blk, 0, stream>>>(x, W_in0, b0, P, PART,
      512, 32, 32, 8192, 0L, 16384L, 512L, 512L, 1, 0);
  // layer 0 recurrence
  rnn_seq<<<dim3(16), dim3(1024), 0, stream>>>(P, Wh0, h, 262144L);
  // P = h0 @ W_in_rest[:,0] + b_rest[:,0]
  gemm_mfma<1><<<dim3(16,16,1), blk, 0, stream>>>(h, W_inr, b_r, P, PART,
      512, 512, 24576, 8192, 1536L, 524288L, 1024L, 512L, 1, 0);
  rnn_seq<<<dim3(16), dim3(1024), 0, stream>>>(P, Wh_r, h + 512, 524288L);
  // P = h1 @ W_in_rest[:,1] + b_rest[:,1]
  gemm_mfma<1><<<dim3(16,16,1), blk, 0, stream>>>(h + 512, W_inr + 262144, b_r + 512, P, PART,
      512, 512, 24576, 8192, 1536L, 524288L, 1024L, 512L, 1, 0);
  rnn_seq<<<dim3(16), dim3(1024), 0, stream>>>(P, Wh_r + 262144, h + 1024, 524288L);
  // FF1: gelu(cat @ W_ff1 + b_ff1) — 512 blocks = 2 WG/CU
  gemm_mfma<2><<<dim3(32,16,1), blk, 0, stream>>>(h, W_ff1, b_ff1, FF, PART,
      2048, 1536, 24576, 32768, 1536L, 3145728L, 2048L, 2048L, 1, 2);
  // FF2 (split-2): ENC = FF @ W_ff2 + b_ff2 — 512 blocks
  gemm_mfma<1><<<dim3(16,16,2), blk, 0, stream>>>(FF, W_ff2, b_ff2, ENC, PART,
      512, 2048, 32768, 8192, 2048L, 1048576L, 512L, 512L, 2, 0);
  reduce_ep<<<dim3(4096), blk, 0, stream>>>(PART, b_ff2, ENC,
      2, 512, 8192, 512L, 512L, 0, 16*128*512, 16);
  // decoder: Z0 = tanh(ENC @ W_d0 + b_d0)   (split-8)
  gemm_mfma<2><<<dim3(32,1,8), blk, 0, stream>>>(ENC, W_d0, b_d0, Z0, PART,
      2048, 8192, 8192, 2048, 0L, 0L, 0L, 0L, 8, 0);
  reduce_ep<<<dim3(1024), blk, 0, stream>>>(PART, b_d0, Z0,
      8, 2048, 2048, 0L, 0L, 1, 128*2048, 1);
  // Z1 = tanh(Z0 @ W_dmid[0] + b_dmid[0])
  gemm_mfma<2><<<dim3(32,1,8), blk, 0, stream>>>(Z0, W_dmid, b_dmid, Z1, PART,
      2048, 2048, 2048, 2048, 0L, 0L, 0L, 0L, 8, 0);
  reduce_ep<<<dim3(1024), blk, 0, stream>>>(PART, b_dmid, Z1,
      8, 2048, 2048, 0L, 0L, 1, 128*2048, 1);
  // Z2 = tanh(Z1 @ W_dmid[1] + b_dmid[1])
  gemm_mfma<2><<<dim3(32,1,8), blk, 0, stream>>>(Z1, W_dmid + 4194304, b_dmid + 2048, Z2, PART,
      2048, 2048, 2048, 2048, 0L, 0L, 0L, 0L, 8, 0);
  reduce_ep<<<dim3(1024), blk, 0, stream>>>(PART, b_dmid + 2048, Z2,
      8, 2048, 2048, 0L, 0L, 1, 128*2048, 1);
  // Y = Z2 @ W_dout + b_dout -> d_out [1,128,1024]
  gemm_mfma<1><<<dim3(32,1,8), blk, 0, stream>>>(Z2, W_dout, b_dout, (float*)d_out, PART,
      1024, 2048, 2048, 1024, 0L, 0L, 0L, 0L, 8, 0);
  reduce_ep<<<dim3(512), blk, 0, stream>>>(PART, b_dout, (float*)d_out,
      8, 1024, 1024, 0L, 0L, 0, 128*1024, 1);
}